// Round 7
// baseline (977.102 us; speedup 1.0000x reference)
//
#include <hip/hip_runtime.h>

// Temporal GraphSAGE, P=4 periods, C=128, L=2 (reference constants).
// R6: fat-register GEMM — all 16 A fragments hoisted into one load burst,
// B double-buffered across k-steps, __launch_bounds__(256,2) so the
// allocator can actually pipeline (R5's (256,3) -> 80 VGPRs serialized the
// loads: 60k cyc/wave measured). aggk skips deg==0 rows; gemm exec-masks
// A2 fragment loads with deg>0 instead.

#define CD 128

typedef __attribute__((ext_vector_type(8))) short s16x8;
typedef __attribute__((ext_vector_type(4))) float f32x4;

static __device__ __forceinline__ unsigned short f2bf(float f) {
  unsigned u = __float_as_uint(f);
  u += 0x7FFF + ((u >> 16) & 1);   // round-to-nearest-even
  return (unsigned short)(u >> 16);
}
static __device__ __forceinline__ float bf2f(unsigned us) {
  return __uint_as_float(us << 16);
}

// ---- histogram: per-(period,dst) degree + involved bitmask ----
__global__ __launch_bounds__(256) void histk(const int* __restrict__ ntime,
    const int* __restrict__ eidx, int* __restrict__ deg_pd, int* __restrict__ involved,
    const int* __restrict__ minp, const int* __restrict__ up, int N, int E) {
  int e = blockIdx.x * 256 + threadIdx.x;
  if (e >= E) return;
  int s = eidx[e], d = eidx[E + e];
  int ts = ntime[s], td = ntime[d];
  int m = ts > td ? ts : td;
  int p = (m - minp[0]) / up[0];
  atomicAdd(&deg_pd[p * N + d], 1);
  atomicOr(&involved[s], 1 << p);
  atomicOr(&involved[d], 1 << p);
}

// ---- exclusive scan (3-phase) ----
__global__ __launch_bounds__(256) void scan1(const int* __restrict__ in,
    int* __restrict__ out, int* __restrict__ bsums, int M) {
  __shared__ int lds[256];
  int tid = threadIdx.x;
  int base = blockIdx.x * 1024 + tid * 4;
  int v0 = base + 0 < M ? in[base + 0] : 0;
  int v1 = base + 1 < M ? in[base + 1] : 0;
  int v2 = base + 2 < M ? in[base + 2] : 0;
  int v3 = base + 3 < M ? in[base + 3] : 0;
  int s = v0 + v1 + v2 + v3;
  lds[tid] = s;
  __syncthreads();
  for (int off = 1; off < 256; off <<= 1) {
    int t = tid >= off ? lds[tid - off] : 0;
    __syncthreads();
    lds[tid] += t;
    __syncthreads();
  }
  int run = lds[tid] - s;
  if (base + 0 < M) out[base + 0] = run; run += v0;
  if (base + 1 < M) out[base + 1] = run; run += v1;
  if (base + 2 < M) out[base + 2] = run; run += v2;
  if (base + 3 < M) out[base + 3] = run;
  if (tid == 255) bsums[blockIdx.x] = lds[255];
}

__global__ __launch_bounds__(256) void scan2(int* __restrict__ b, int M) {
  __shared__ int lds[256];
  int tid = threadIdx.x;
  int base = tid * 4;
  int v0 = base + 0 < M ? b[base + 0] : 0;
  int v1 = base + 1 < M ? b[base + 1] : 0;
  int v2 = base + 2 < M ? b[base + 2] : 0;
  int v3 = base + 3 < M ? b[base + 3] : 0;
  int s = v0 + v1 + v2 + v3;
  lds[tid] = s;
  __syncthreads();
  for (int off = 1; off < 256; off <<= 1) {
    int t = tid >= off ? lds[tid - off] : 0;
    __syncthreads();
    lds[tid] += t;
    __syncthreads();
  }
  int run = lds[tid] - s;
  if (base + 0 < M) b[base + 0] = run; run += v0;
  if (base + 1 < M) b[base + 1] = run; run += v1;
  if (base + 2 < M) b[base + 2] = run; run += v2;
  if (base + 3 < M) b[base + 3] = run;
}

__global__ __launch_bounds__(256) void scan3(int* __restrict__ out,
    const int* __restrict__ bsums, int M) {
  int add = bsums[blockIdx.x];
  int idx = blockIdx.x * 1024 + threadIdx.x;
#pragma unroll
  for (int k = 0; k < 4; ++k) {
    int i = idx + k * 256;
    if (i < M) out[i] += add;
  }
}

// ---- fill CSR col array; row_ptr doubles as cursor ----
__global__ __launch_bounds__(256) void fillk(const int* __restrict__ ntime,
    const int* __restrict__ eidx, int* __restrict__ row_ptr, int* __restrict__ col,
    const int* __restrict__ minp, const int* __restrict__ up, int N, int E) {
  int e = blockIdx.x * 256 + threadIdx.x;
  if (e >= E) return;
  int s = eidx[e], d = eidx[E + e];
  int ts = ntime[s], td = ntime[d];
  int m = ts > td ? ts : td;
  int p = (m - minp[0]) / up[0];
  int pos = atomicAdd(&row_ptr[p * N + d], 1);
  col[pos] = s;
}

// ---- weights: transpose + bf16, fragment-linear layout ----
// wt[l][q][n][j]: q in [0,32) = 16B k-block over K=256, n = output col,
// content k = q*8+j; k<128 from w_root[l][k][n], else w_nbr[l][k-128][n].
__global__ __launch_bounds__(256) void wprep(const float* __restrict__ wroot,
    const float* __restrict__ wnbr, unsigned short* __restrict__ wt, int total) {
  int t = blockIdx.x * 256 + threadIdx.x;
  if (t >= total) return;
  int l = t >> 12;
  int rem = t & 4095;
  int q = rem >> 7;
  int n = rem & 127;
  const float* w0 = wroot + l * CD * CD;
  const float* w1 = wnbr + l * CD * CD;
  unsigned short o[8];
#pragma unroll
  for (int j = 0; j < 8; ++j) {
    int k = q * 8 + j;
    float v = (k < CD) ? w0[k * CD + n] : w1[(k - CD) * CD + n];
    o[j] = f2bf(v);
  }
  uint4 pk;
  pk.x = (unsigned)o[0] | ((unsigned)o[1] << 16);
  pk.y = (unsigned)o[2] | ((unsigned)o[3] << 16);
  pk.z = (unsigned)o[4] | ((unsigned)o[5] << 16);
  pk.w = (unsigned)o[6] | ((unsigned)o[7] << 16);
  *(uint4*)(wt + (size_t)l * 32768 + ((size_t)q * CD + n) * 8) = pk;
}

// ---- x_bf init (+ fp32 mirror of seed rows for the head) ----
__global__ __launch_bounds__(256) void xprep(const float* __restrict__ x,
    float* __restrict__ x32, unsigned short* __restrict__ xb, int nseed, int total4) {
  int t = blockIdx.x * 256 + threadIdx.x;
  if (t >= total4) return;
  size_t i = (size_t)t * 4;
  float4 v = *(const float4*)(x + i);
  uint2 pk;
  pk.x = (unsigned)f2bf(v.x) | ((unsigned)f2bf(v.y) << 16);
  pk.y = (unsigned)f2bf(v.z) | ((unsigned)f2bf(v.w) << 16);
  *(uint2*)(xb + i) = pk;
  if ((int)(i >> 7) < nseed) *(float4*)(x32 + i) = v;
}

// ---- pull aggregation: 16-lane group per dst; deg==0 rows are SKIPPED
// (gemm masks their A2 fragments instead) ----
__global__ __launch_bounds__(256) void aggk(const unsigned short* __restrict__ hbf,
    unsigned short* __restrict__ aggbf, const int* __restrict__ row_ptr,
    const int* __restrict__ deg_pd, const int* __restrict__ col, int p, int N) {
  int d = blockIdx.x * 16 + (threadIdx.x >> 4);
  if (d >= N) return;
  int lane = threadIdx.x & 15;
  int key = p * N + d;
  int dg = deg_pd[key];
  if (dg == 0) return;              // no write: gemm zero-masks these rows
  int start = row_ptr[key] - dg;
  float a[8];
#pragma unroll
  for (int i = 0; i < 8; ++i) a[i] = 0.f;
  for (int j = 0; j < dg; ++j) {
    int s = col[start + j];
    uint4 r = *(const uint4*)(hbf + (size_t)s * CD + lane * 8);
    a[0] += bf2f(r.x & 0xffffu); a[1] += bf2f(r.x >> 16);
    a[2] += bf2f(r.y & 0xffffu); a[3] += bf2f(r.y >> 16);
    a[4] += bf2f(r.z & 0xffffu); a[5] += bf2f(r.z >> 16);
    a[6] += bf2f(r.w & 0xffffu); a[7] += bf2f(r.w >> 16);
  }
  float sc = 1.0f / (float)dg;
  uint4 outv;
  outv.x = (unsigned)f2bf(a[0] * sc) | ((unsigned)f2bf(a[1] * sc) << 16);
  outv.y = (unsigned)f2bf(a[2] * sc) | ((unsigned)f2bf(a[3] * sc) << 16);
  outv.z = (unsigned)f2bf(a[4] * sc) | ((unsigned)f2bf(a[5] * sc) << 16);
  outv.w = (unsigned)f2bf(a[6] * sc) | ((unsigned)f2bf(a[7] * sc) << 16);
  *(uint4*)(aggbf + (size_t)d * CD + lane * 8) = outv;
}

// ---- MFMA GEMM + bias + LN (+relu -> h_bf | +residual -> x_bf [& x32 seeds]) ----
// 256 threads = 4 waves; block tile 128x128; wave = 32 rows x 128 cols
// = 2x8 tiles of 16x16x32. K=256 from [A1|A2]. No LDS/barriers.
// All 16 A fragments loaded in one up-front burst (A2 exec-masked by deg>0);
// B fragments double-buffered across the 8 k-steps.
__global__ __launch_bounds__(256, 2) void gemm_mfma(
    const unsigned short* __restrict__ A1, const unsigned short* __restrict__ A2,
    const int* __restrict__ degp,
    const unsigned short* __restrict__ wt,
    const float* __restrict__ bias, const float* __restrict__ lng,
    const float* __restrict__ lnb,
    unsigned short* __restrict__ hout,
    float* __restrict__ x32, unsigned short* __restrict__ xbf,
    const int* __restrict__ involved, int pbit, int mode, int nseed, int N) {
  int tid = threadIdx.x;
  int w = tid >> 6;
  int lane = tid & 63;
  int l15 = lane & 15;
  int quad = lane >> 4;
  int rbase = blockIdx.x * 128;

  int row[2];
  bool hasdeg[2];
#pragma unroll
  for (int rt = 0; rt < 2; ++rt) {
    int r = rbase + w * 32 + rt * 16 + l15;
    row[rt] = r < N ? r : N - 1;
    hasdeg[rt] = degp[row[rt]] > 0;
  }

  // ---- A burst: 16 independent 16B loads, all in flight together ----
  // frag f: kc-half = f>>1 (koff 0/64), ks = f&1; k-block = (ks*4+quad)
  s16x8 a1f[2][4], a2f[2][4];
#pragma unroll
  for (int rt = 0; rt < 2; ++rt) {
    const unsigned short* b1 = A1 + (size_t)row[rt] * CD;
#pragma unroll
    for (int f = 0; f < 4; ++f) {
      int off = (f >> 1) * 64 + ((f & 1) * 4 + quad) * 8;
      a1f[rt][f] = *(const s16x8*)(b1 + off);
    }
  }
#pragma unroll
  for (int rt = 0; rt < 2; ++rt) {
    const unsigned short* b2 = A2 + (size_t)row[rt] * CD;
#pragma unroll
    for (int f = 0; f < 4; ++f) {
      int off = (f >> 1) * 64 + ((f & 1) * 4 + quad) * 8;
      s16x8 v = (s16x8)(short)0;
      if (hasdeg[rt]) v = *(const s16x8*)(b2 + off);  // exec-masked load
      a2f[rt][f] = v;
    }
  }

  f32x4 acc[2][8];
#pragma unroll
  for (int rt = 0; rt < 2; ++rt)
#pragma unroll
    for (int ct = 0; ct < 8; ++ct) acc[rt][ct] = (f32x4)(0.f);

  // ---- B double-buffered over 8 steps; step s: q = s*4+quad ----
  s16x8 bcur[8], bnxt[8];
  {
    const unsigned short* wq = wt + ((size_t)(0 * 4 + quad) * CD + l15) * 8;
#pragma unroll
    for (int ct = 0; ct < 8; ++ct)
      bcur[ct] = *(const s16x8*)(wq + (size_t)ct * 128);
  }
#pragma unroll
  for (int s = 0; s < 8; ++s) {
    if (s < 7) {
      const unsigned short* wq = wt + ((size_t)((s + 1) * 4 + quad) * CD + l15) * 8;
#pragma unroll
      for (int ct = 0; ct < 8; ++ct)
        bnxt[ct] = *(const s16x8*)(wq + (size_t)ct * 128);
    }
    int f = s & 3;                  // (kc&1)*2 + ks
#pragma unroll
    for (int rt = 0; rt < 2; ++rt) {
      s16x8 af = (s < 4) ? a1f[rt][f] : a2f[rt][f];
#pragma unroll
      for (int ct = 0; ct < 8; ++ct)
        acc[rt][ct] = __builtin_amdgcn_mfma_f32_16x16x32_bf16(
            af, bcur[ct], acc[rt][ct], 0, 0, 0);
    }
#pragma unroll
    for (int ct = 0; ct < 8; ++ct) bcur[ct] = bnxt[ct];
  }

  // ---- epilogue: bias + LayerNorm across the 16-lane row group ----
  float bb[8], gg[8], eb[8];
#pragma unroll
  for (int ct = 0; ct < 8; ++ct) {
    int c = ct * 16 + l15;
    bb[ct] = bias[c]; gg[ct] = lng[c]; eb[ct] = lnb[c];
  }
#pragma unroll
  for (int rt = 0; rt < 2; ++rt) {
#pragma unroll
    for (int reg = 0; reg < 4; ++reg) {
      int r = rbase + w * 32 + rt * 16 + quad * 4 + reg;
      float vals[8];
      float s = 0.f, ss = 0.f;
#pragma unroll
      for (int ct = 0; ct < 8; ++ct) {
        float v = acc[rt][ct][reg] + bb[ct];
        vals[ct] = v;
        s += v; ss += v * v;
      }
#pragma unroll
      for (int m = 1; m <= 8; m <<= 1) {
        s  += __shfl_xor(s, m, 64);
        ss += __shfl_xor(ss, m, 64);
      }
      float mu  = s * (1.0f / CD);
      float var = ss * (1.0f / CD) - mu * mu;
      float rs  = rsqrtf(var + 1e-5f);
      if (r < N) {
        if (mode == 0) {
#pragma unroll
          for (int ct = 0; ct < 8; ++ct) {
            float o = (vals[ct] - mu) * rs * gg[ct] + eb[ct];
            o = fmaxf(o, 0.f);
            hout[(size_t)r * CD + ct * 16 + l15] = f2bf(o);
          }
        } else if ((involved[r] >> pbit) & 1) {
          bool seed = r < nseed;
#pragma unroll
          for (int ct = 0; ct < 8; ++ct) {
            float o = (vals[ct] - mu) * rs * gg[ct] + eb[ct];
            size_t idx = (size_t)r * CD + ct * 16 + l15;
            float xn = bf2f(xbf[idx]) + o;
            xbf[idx] = f2bf(xn);
            if (seed) x32[idx] += o;
          }
        }
      }
    }
  }
}

// ---- head (reads fp32 seed mirror) ----
__global__ __launch_bounds__(256) void headk(const float* __restrict__ x,
    const float* __restrict__ hw, const float* __restrict__ hb,
    float* __restrict__ out, int seeds) {
  int wave = threadIdx.x >> 6;
  int lane = threadIdx.x & 63;
  int row = blockIdx.x * 4 + wave;
  if (row >= seeds) return;
  const float* xp = x + (size_t)row * CD;
  float v = xp[lane] * hw[lane] + xp[64 + lane] * hw[64 + lane];
#pragma unroll
  for (int m = 1; m < 64; m <<= 1) v += __shfl_xor(v, m, 64);
  if (lane == 0) out[row] = v + hb[0];
}

extern "C" void kernel_launch(void* const* d_in, const int* in_sizes, int n_in,
                              void* d_out, int out_size, void* d_ws, size_t ws_size,
                              hipStream_t stream) {
  const float* x     = (const float*)d_in[0];
  const int*   ntime = (const int*)d_in[1];
  const int*   eidx  = (const int*)d_in[2];
  const float* wroot = (const float*)d_in[3];
  const float* wnbr  = (const float*)d_in[4];
  const float* bias  = (const float*)d_in[5];
  const float* lng   = (const float*)d_in[6];
  const float* lnb   = (const float*)d_in[7];
  const float* headw = (const float*)d_in[8];
  const float* headb = (const float*)d_in[9];
  const int*   minp  = (const int*)d_in[10];
  const int*   up    = (const int*)d_in[12];

  int N = in_sizes[0] / CD;
  int E = in_sizes[2] / 2;
  const int P = 4;
  int M = P * N;
  int nseed = out_size;   // OUT=1 per reference

  size_t off = 0;
  auto alloc = [&](size_t bytes) {
    void* p = (char*)d_ws + off;
    off += (bytes + 255) & ~(size_t)255;
    return p;
  };
  unsigned short* x_bf   = (unsigned short*)alloc((size_t)N * CD * 2);
  unsigned short* h_bf   = (unsigned short*)alloc((size_t)N * CD * 2);
  unsigned short* agg_bf = (unsigned short*)alloc((size_t)N * CD * 2);
  float*          x32    = (float*)alloc((size_t)nseed * CD * 4);
  unsigned short* wt     = (unsigned short*)alloc(2 * 32768 * 2);
  int* deg_pd   = (int*)alloc((size_t)M * 4);
  int* row_ptr  = (int*)alloc((size_t)M * 4);
  int* col      = (int*)alloc((size_t)E * 4);
  int* involved = (int*)alloc((size_t)N * 4);
  int* bsums    = (int*)alloc(4096);
  (void)ws_size;

  hipMemsetAsync(deg_pd, 0, (size_t)M * 4, stream);
  hipMemsetAsync(involved, 0, (size_t)N * 4, stream);

  int egrid = (E + 255) / 256;
  int NB = (M + 1023) / 1024;
  int ggrid = (N + 127) / 128;
  int agrid = (N + 15) / 16;

  xprep<<<(N * 32 + 255) / 256, 256, 0, stream>>>(x, x32, x_bf, nseed, N * 32);
  wprep<<<(8192 + 255) / 256, 256, 0, stream>>>(wroot, wnbr, wt, 8192);
  histk<<<egrid, 256, 0, stream>>>(ntime, eidx, deg_pd, involved, minp, up, N, E);
  scan1<<<NB, 256, 0, stream>>>(deg_pd, row_ptr, bsums, M);
  scan2<<<1, 256, 0, stream>>>(bsums, NB);
  scan3<<<NB, 256, 0, stream>>>(row_ptr, bsums, M);
  fillk<<<egrid, 256, 0, stream>>>(ntime, eidx, row_ptr, col, minp, up, N, E);

  for (int p = 0; p < P; ++p) {
    const int* degp = deg_pd + (size_t)p * N;
    aggk<<<agrid, 256, 0, stream>>>(x_bf, agg_bf, row_ptr, deg_pd, col, p, N);
    gemm_mfma<<<ggrid, 256, 0, stream>>>(x_bf, agg_bf, degp, wt,
        bias, lng, lnb, h_bf, nullptr, nullptr, nullptr, -1, 0, nseed, N);
    aggk<<<agrid, 256, 0, stream>>>(h_bf, agg_bf, row_ptr, deg_pd, col, p, N);
    gemm_mfma<<<ggrid, 256, 0, stream>>>(h_bf, agg_bf, degp, wt + 32768,
        bias + CD, lng + CD, lnb + CD, nullptr, x32, x_bf, involved, p, 1, nseed, N);
  }
  headk<<<(nseed + 3) / 4, 256, 0, stream>>>(x32, headw, headb, (float*)d_out, nseed);
}